// Round 1
// baseline (507.129 us; speedup 1.0000x reference)
//
#include <hip/hip_runtime.h>
#include <stdint.h>

// Problem constants
#define D_DIM   1024
#define NTOK    4096      // G*S
#define NROUTE  8192      // NTOK * K(=2)
#define E_NUM   16
#define ESLOT   17        // 16 routed + 1 shared
#define MAXROWS 14336     // max padded entry rows: <=10224 routed + 4096 shared
#define BM      128
#define BN      64
#define BK      32
#define MAXTILES 112      // MAXROWS / BM

typedef __attribute__((ext_vector_type(8))) short bf16x8;  // 8 bf16 (4 VGPRs) - guide-verified
typedef __attribute__((ext_vector_type(4))) float f32x4;

static __device__ __forceinline__ unsigned short f2b(float f) {  // fp32 -> bf16 RNE
  unsigned u = __builtin_bit_cast(unsigned, f);
  u += 0x7fffu + ((u >> 16) & 1u);
  return (unsigned short)(u >> 16);
}
static __device__ __forceinline__ float b2f(unsigned short h) {
  unsigned u = ((unsigned)h) << 16;
  return __builtin_bit_cast(float, u);
}

// CK-style async global->LDS, 16B per lane. dest = M0(wave-uniform) + lane*16.
static __device__ __forceinline__ void gload_lds16(const void* src, void* lds) {
  unsigned m0v = __builtin_amdgcn_readfirstlane((unsigned)(uintptr_t)lds);
  asm volatile("s_mov_b32 m0, %0\n\t"
               "global_load_lds_dwordx4 %1, off"
               :: "s"(m0v), "v"(src) : "memory");
}

// ---------------- x fp32 -> bf16 (+ zero entry-token array) ----------------
__global__ void k_convert_x(const float* __restrict__ x, unsigned short* __restrict__ xb,
                            int* __restrict__ etok) {
  long gid = (long)blockIdx.x * 256 + threadIdx.x;
  if (gid < MAXROWS) etok[gid] = 0;   // padding entries -> token 0 (safe row)
  long i = gid * 4;
  float4 v = *(const float4*)(x + i);
  ushort4 o = make_ushort4(f2b(v.x), f2b(v.y), f2b(v.z), f2b(v.w));
  *(ushort4*)(xb + i) = o;
}

// ---------------- weights fp32 [K][N] -> bf16 transposed [N][K] ----------------
// Wt layout: [3][17][1024][1024] bf16, slot = m*17+e; Wt[slot][n][k] = Wsrc[k][n]
__global__ void k_trans_w(const float* __restrict__ Wg, const float* __restrict__ Wu,
                          const float* __restrict__ Wd, const float* __restrict__ sg,
                          const float* __restrict__ su, const float* __restrict__ sd,
                          unsigned short* __restrict__ Wt) {
  int bid = blockIdx.x;
  int slot = bid >> 8;          // 0..50
  int tilei = bid & 255;        // 16x16 tiles of 64x64
  int kt = (tilei >> 4) * 64;
  int nt = (tilei & 15) * 64;
  int m = slot / ESLOT, e = slot % ESLOT;
  const float* src;
  if (e < E_NUM) src = (m == 0 ? Wg : m == 1 ? Wu : Wd) + (size_t)e * (D_DIM * D_DIM);
  else           src = (m == 0 ? sg : m == 1 ? su : sd);

  __shared__ float tile[64][65];   // +1 pad: conflict-free column reads
  int tid = threadIdx.x;
#pragma unroll
  for (int it = 0; it < 4; it++) {
    int flat = it * 1024 + tid * 4;
    int r = flat >> 6, c = flat & 63;
    float4 v = *(const float4*)&src[(size_t)(kt + r) * D_DIM + nt + c];
    tile[r][c] = v.x; tile[r][c + 1] = v.y; tile[r][c + 2] = v.z; tile[r][c + 3] = v.w;
  }
  __syncthreads();
  unsigned short* dst = Wt + (size_t)slot * (D_DIM * D_DIM);
#pragma unroll
  for (int it = 0; it < 4; it++) {
    int flat = it * 1024 + tid * 4;
    int n = flat >> 6, k = flat & 63;
    ushort4 o = make_ushort4(f2b(tile[k][n]), f2b(tile[k + 1][n]),
                             f2b(tile[k + 2][n]), f2b(tile[k + 3][n]));
    *(ushort4*)&dst[(size_t)(nt + n) * D_DIM + kt + k] = o;
  }
}

// ---------------- routing dispatch (1 block) ----------------
__global__ void k_dispatch(const int* __restrict__ idx,
                           int* __restrict__ etok, int* __restrict__ pos2,
                           int* __restrict__ ebase, int* __restrict__ tile_e,
                           int* __restrict__ tile_r, int* __restrict__ ntp) {
  __shared__ int cnt[ESLOT];
  __shared__ int cur[E_NUM];
  __shared__ int basz[ESLOT + 1];
  int tid = threadIdx.x;  // 256
  if (tid < ESLOT) cnt[tid] = 0;
  __syncthreads();
  for (int i = tid; i < NROUTE; i += 256) atomicAdd(&cnt[idx[i]], 1);
  __syncthreads();
  if (tid == 0) {
    int off = 0;
    for (int e = 0; e < E_NUM; e++) { basz[e] = off; off += ((cnt[e] + BM - 1) / BM) * BM; }
    basz[E_NUM] = off;                 // shared expert segment (4096, already x128)
    basz[E_NUM + 1] = off + NTOK;
    int t = 0;
    for (int e = 0; e <= E_NUM; e++) {
      int c = (e == E_NUM) ? NTOK : cnt[e];
      for (int r = 0; r < c; r += BM) { tile_e[t] = e; tile_r[t] = basz[e] + r; t++; }
    }
    *ntp = t;                          // <= 111
  }
  if (tid < E_NUM) cur[tid] = 0;
  __syncthreads();
  for (int i = tid; i < NROUTE; i += 256) {
    int e = idx[i];
    int p = basz[e] + atomicAdd(&cur[e], 1);
    etok[p] = i >> 1;                  // token id (K=2)
    pos2[i] = p;                       // where (token,k)'s y lands
  }
  for (int i = tid; i < NTOK; i += 256) etok[basz[E_NUM] + i] = i;
  if (tid < ESLOT + 1) ebase[tid] = basz[tid];
}

// ---------------- grouped GEMM: C[rows x D] = A[rows x D] @ W[e]  ----------------
// NMAT=2: A = gathered x_bf rows; out = silu(g)*u (bf16).  NMAT=1: A = Aact; out = y.
// LDS sub-tiled [kq][row][8] so staging (linear lane order) AND frag ds_read_b128
// are both 2-way-max bank aliasing (free).
template <int NMAT>
__global__ void __launch_bounds__(256)
k_gemm(const unsigned short* __restrict__ Abase, const unsigned short* __restrict__ Wt,
       int m0, const int* __restrict__ etok,
       const int* __restrict__ tile_e, const int* __restrict__ tile_r,
       const int* __restrict__ ntp, unsigned short* __restrict__ Out) {
  int bt = blockIdx.y;
  if (bt >= *ntp) return;
  int e = tile_e[bt];
  int row0 = tile_r[bt];
  int n0 = blockIdx.x * BN;

  __shared__ __align__(16) unsigned short sA[4 * BM * 8];          // 8KB  [kq][128][8]
  __shared__ __align__(16) unsigned short sB[NMAT][4 * BN * 8];    // 4KB each [kq][64][8]

  int tid = threadIdx.x;
  int wid = tid >> 6, lane = tid & 63;
  int wm = wid >> 1, wn = wid & 1;

  // A staging: instr i covers slots i*256+tid; slot -> kq=slot>>7, row=slot&127
  int arow = tid & 127;
  int akq0 = tid >> 7;  // 0/1; instr1 uses akq0+2
  size_t tokrow = etok ? (size_t)etok[row0 + arow] : (size_t)(row0 + arow);
  const unsigned short* aptr = Abase + tokrow * D_DIM;

  // B staging: slot=tid -> kq=tid>>6, n=tid&63
  int bn = tid & 63, bkq = tid >> 6;
  const unsigned short* bptr[NMAT];
#pragma unroll
  for (int m = 0; m < NMAT; m++)
    bptr[m] = Wt + ((size_t)(m0 + m) * ESLOT + e) * (size_t)(D_DIM * D_DIM)
               + (size_t)(n0 + bn) * D_DIM + bkq * 8;

  char* sAb = (char*)sA;
  int a_off[4], b_off[2];
#pragma unroll
  for (int fm = 0; fm < 4; fm++)
    a_off[fm] = ((lane >> 4) * BM + wm * 64 + fm * 16 + (lane & 15)) * 16;
#pragma unroll
  for (int fn = 0; fn < 2; fn++)
    b_off[fn] = ((lane >> 4) * BN + wn * 32 + fn * 16 + (lane & 15)) * 16;

  f32x4 acc[NMAT][4][2] = {};

  for (int kk = 0; kk < D_DIM; kk += BK) {
    gload_lds16(aptr + kk + akq0 * 8,       sAb + (0 * 256 + wid * 64) * 16);
    gload_lds16(aptr + kk + (akq0 + 2) * 8, sAb + (1 * 256 + wid * 64) * 16);
#pragma unroll
    for (int m = 0; m < NMAT; m++)
      gload_lds16(bptr[m] + kk, (char*)sB[m] + wid * 64 * 16);
    asm volatile("s_waitcnt vmcnt(0)" ::: "memory");
    __syncthreads();
    bf16x8 af[4];
#pragma unroll
    for (int fm = 0; fm < 4; fm++) af[fm] = *(const bf16x8*)(sAb + a_off[fm]);
#pragma unroll
    for (int m = 0; m < NMAT; m++) {
      bf16x8 b0 = *(const bf16x8*)((char*)sB[m] + b_off[0]);
      bf16x8 b1 = *(const bf16x8*)((char*)sB[m] + b_off[1]);
#pragma unroll
      for (int fm = 0; fm < 4; fm++) {
        acc[m][fm][0] = __builtin_amdgcn_mfma_f32_16x16x32_bf16(af[fm], b0, acc[m][fm][0], 0, 0, 0);
        acc[m][fm][1] = __builtin_amdgcn_mfma_f32_16x16x32_bf16(af[fm], b1, acc[m][fm][1], 0, 0, 0);
      }
    }
    __syncthreads();
  }

  // epilogue: C/D layout col=lane&15, row=(lane>>4)*4+j (m89/m91 verified)
  int crow = row0 + wm * 64 + (lane >> 4) * 4;
  int ccol = n0 + wn * 32 + (lane & 15);
#pragma unroll
  for (int fm = 0; fm < 4; fm++)
#pragma unroll
    for (int fn = 0; fn < 2; fn++)
#pragma unroll
      for (int j = 0; j < 4; j++) {
        int r = crow + fm * 16 + j;
        int c = ccol + fn * 16;
        float v;
        if constexpr (NMAT == 2) {
          float g = acc[0][fm][fn][j];
          float u = acc[1][fm][fn][j];
          v = g / (1.f + __expf(-g)) * u;   // silu(g)*u
        } else {
          v = acc[0][fm][fn][j];
        }
        Out[(size_t)r * D_DIM + c] = f2b(v);
      }
}

// ---------------- combine: out = w0*Y[p0] + w1*Y[p1] + Y[shared] ----------------
__global__ void k_combine(const unsigned short* __restrict__ Y, const float* __restrict__ w,
                          const int* __restrict__ pos2, const int* __restrict__ ebase,
                          float* __restrict__ out) {
  int t = blockIdx.x;
  int tid = threadIdx.x;
  int p0 = pos2[t * 2], p1 = pos2[t * 2 + 1];
  float w0 = w[t * 2], w1 = w[t * 2 + 1];
  int ps = ebase[E_NUM] + t;
  int c = tid * 4;
  ushort4 ya = *(const ushort4*)(Y + (size_t)p0 * D_DIM + c);
  ushort4 yb = *(const ushort4*)(Y + (size_t)p1 * D_DIM + c);
  ushort4 ys = *(const ushort4*)(Y + (size_t)ps * D_DIM + c);
  float4 o;
  o.x = w0 * b2f(ya.x) + w1 * b2f(yb.x) + b2f(ys.x);
  o.y = w0 * b2f(ya.y) + w1 * b2f(yb.y) + b2f(ys.y);
  o.z = w0 * b2f(ya.z) + w1 * b2f(yb.z) + b2f(ys.z);
  o.w = w0 * b2f(ya.w) + w1 * b2f(yb.w) + b2f(ys.w);
  *(float4*)(out + (size_t)t * D_DIM + c) = o;
}

extern "C" void kernel_launch(void* const* d_in, const int* in_sizes, int n_in,
                              void* d_out, int out_size, void* d_ws, size_t ws_size,
                              hipStream_t stream) {
  (void)in_sizes; (void)n_in; (void)out_size; (void)ws_size;
  const float* x  = (const float*)d_in[0];
  const float* w  = (const float*)d_in[1];
  const int*   idx = (const int*)d_in[2];
  const float* Wg = (const float*)d_in[5];
  const float* Wu = (const float*)d_in[6];
  const float* Wd = (const float*)d_in[7];
  const float* sg = (const float*)d_in[8];
  const float* su = (const float*)d_in[9];
  const float* sd = (const float*)d_in[10];
  float* out = (float*)d_out;

  // workspace layout (bytes)
  char* ws = (char*)d_ws;
  unsigned short* Wt   = (unsigned short*)(ws + 0);            // 3*17*1M*2   = 106,954,752
  unsigned short* xb   = (unsigned short*)(ws + 106954752);    // 4096*1024*2 =   8,388,608
  unsigned short* Aact = (unsigned short*)(ws + 115343360);    // 14336*1024*2=  29,360,128
  unsigned short* Y    = (unsigned short*)(ws + 144703488);    // 14336*1024*2=  29,360,128
  int* etok   = (int*)(ws + 174063616);                        // 14336*4
  int* pos2   = (int*)(ws + 174120960);                        // 8192*4
  int* ebase  = (int*)(ws + 174153728);                        // 18*4 (pad 256)
  int* tile_e = (int*)(ws + 174153984);                        // 112*4 (pad 512)
  int* tile_r = (int*)(ws + 174154496);                        // 112*4 (pad 512)
  int* ntp    = (int*)(ws + 174155008);                        // 4

  k_convert_x<<<4096, 256, 0, stream>>>(x, xb, etok);
  k_trans_w<<<51 * 256, 256, 0, stream>>>(Wg, Wu, Wd, sg, su, sd, Wt);
  k_dispatch<<<1, 256, 0, stream>>>(idx, etok, pos2, ebase, tile_e, tile_r, ntp);
  k_gemm<2><<<dim3(16, MAXTILES), 256, 0, stream>>>(xb, Wt, 0, etok, tile_e, tile_r, ntp, Aact);
  k_gemm<1><<<dim3(16, MAXTILES), 256, 0, stream>>>(Aact, Wt, 2, nullptr, tile_e, tile_r, ntp, Y);
  k_combine<<<NTOK, 256, 0, stream>>>(Y, w, pos2, ebase, out);
}